// Round 1
// baseline (427.103 us; speedup 1.0000x reference)
//
#include <hip/hip_runtime.h>

// Haar 3D DWT, stride-2 2x2x2 depthwise conv with fixed Haar bank.
// x: (2,16,128,128,128) fp32  ->  y: (2,16*8,64,64,64) fp32
// Pure streaming op: 256 MiB in + 256 MiB out, memory-bound (~85us floor).

constexpr int Din = 128, Hin = 128, Win = 128;
constexpr int D2 = 64, H2 = 64, W2 = 64;
constexpr int NC = 32;                    // N*C = 2*16
constexpr size_t PLANE_OUT = (size_t)D2 * H2 * W2;   // 262144 elems per (nc,o) volume
constexpr size_t HW_IN = (size_t)Hin * Win;

__global__ __launch_bounds__(256) void haar3d_kernel(const float* __restrict__ x,
                                                     float* __restrict__ y) {
    const size_t tid = (size_t)blockIdx.x * 256 + threadIdx.x;
    // decomposition: wp (w-block pair) innermost for coalescing
    const int wp = (int)(tid & 31);          // 32 pairs -> 64 w-blocks
    const int h  = (int)((tid >> 5) & 63);
    const int d  = (int)((tid >> 11) & 63);
    const int nc = (int)(tid >> 17);         // [0,32)

    // input slab base: rows (2d+i, 2h+j), 8 consecutive floats starting at 8*wp... 4*wp pairs
    const size_t row0 = (((size_t)nc * Din + 2 * d) * Hin + 2 * h) * Win + 4 * (size_t)wp;
    const float4 v00 = *(const float4*)(x + row0);              // i=0, j=0
    const float4 v01 = *(const float4*)(x + row0 + Win);        // i=0, j=1
    const float4 v10 = *(const float4*)(x + row0 + HW_IN);      // i=1, j=0
    const float4 v11 = *(const float4*)(x + row0 + HW_IN + Win);// i=1, j=1

    // Butterfly. o index bits: bit2 = i(d-axis) hi, bit1 = j(h-axis) hi, bit0 = k(w-axis) hi.
    float o0[8], o1[8];
    {   // block 0 uses (.x,.y) = k0,k1 at w = 2*wp
        float kl00 = v00.x + v00.y, kh00 = v00.x - v00.y;
        float kl01 = v01.x + v01.y, kh01 = v01.x - v01.y;
        float kl10 = v10.x + v10.y, kh10 = v10.x - v10.y;
        float kl11 = v11.x + v11.y, kh11 = v11.x - v11.y;
        float jlkl0 = kl00 + kl01, jhkl0 = kl00 - kl01;
        float jlkh0 = kh00 + kh01, jhkh0 = kh00 - kh01;
        float jlkl1 = kl10 + kl11, jhkl1 = kl10 - kl11;
        float jlkh1 = kh10 + kh11, jhkh1 = kh10 - kh11;
        o0[0] = jlkl0 + jlkl1;  o0[4] = jlkl0 - jlkl1;
        o0[1] = jlkh0 + jlkh1;  o0[5] = jlkh0 - jlkh1;
        o0[2] = jhkl0 + jhkl1;  o0[6] = jhkl0 - jhkl1;
        o0[3] = jhkh0 + jhkh1;  o0[7] = jhkh0 - jhkh1;
    }
    {   // block 1 uses (.z,.w) = k0,k1 at w = 2*wp+1
        float kl00 = v00.z + v00.w, kh00 = v00.z - v00.w;
        float kl01 = v01.z + v01.w, kh01 = v01.z - v01.w;
        float kl10 = v10.z + v10.w, kh10 = v10.z - v10.w;
        float kl11 = v11.z + v11.w, kh11 = v11.z - v11.w;
        float jlkl0 = kl00 + kl01, jhkl0 = kl00 - kl01;
        float jlkh0 = kh00 + kh01, jhkh0 = kh00 - kh01;
        float jlkl1 = kl10 + kl11, jhkl1 = kl10 - kl11;
        float jlkh1 = kh10 + kh11, jhkh1 = kh10 - kh11;
        o1[0] = jlkl0 + jlkl1;  o1[4] = jlkl0 - jlkl1;
        o1[1] = jlkh0 + jlkh1;  o1[5] = jlkh0 - jlkh1;
        o1[2] = jhkl0 + jhkl1;  o1[6] = jhkl0 - jhkl1;
        o1[3] = jhkh0 + jhkh1;  o1[7] = jhkh0 - jhkh1;
    }

    // outputs: y[((nc*8 + o)*64 + d)*4096 + h*64 + 2*wp], float2 per o-plane
    const size_t obase = (size_t)nc * 8 * PLANE_OUT + (size_t)d * (H2 * W2)
                       + (size_t)h * W2 + 2 * (size_t)wp;
#pragma unroll
    for (int o = 0; o < 8; ++o) {
        float2 r;
        r.x = o0[o] * 0.125f;
        r.y = o1[o] * 0.125f;
        *(float2*)(y + obase + (size_t)o * PLANE_OUT) = r;
    }
}

extern "C" void kernel_launch(void* const* d_in, const int* in_sizes, int n_in,
                              void* d_out, int out_size, void* d_ws, size_t ws_size,
                              hipStream_t stream) {
    const float* x = (const float*)d_in[0];
    float* y = (float*)d_out;
    // total threads: 32 * 64 * 64 * 32 = 4,194,304 -> 16384 blocks of 256
    const int total = NC * D2 * H2 * (W2 / 2);
    haar3d_kernel<<<total / 256, 256, 0, stream>>>(x, y);
}

// Round 3
// 420.953 us; speedup vs baseline: 1.0146x; 1.0146x over previous
//
#include <hip/hip_runtime.h>

// Haar 3D DWT, stride-2 2x2x2 depthwise conv with fixed Haar bank.
// x: (2,16,128,128,128) fp32  ->  y: (2,16*8,64,64,64) fp32
// Streaming op: 268 MB in + 268 MB out => ~85us floor @ 6.3 TB/s.
// R3: same as R2 but nontemporal builtins take native ext_vector_type
//     (HIP float4 is a class -> rejected by the builtin).

typedef float vf4 __attribute__((ext_vector_type(4)));

constexpr int Din = 128, Hin = 128, Win = 128;
constexpr int D2 = 64, H2 = 64, W2 = 64;
constexpr int NC = 32;                                 // N*C = 2*16
constexpr size_t PLANE_OUT = (size_t)D2 * H2 * W2;     // 262144 elems per (nc,o) volume
constexpr size_t HW_IN = (size_t)Hin * Win;

__global__ __launch_bounds__(256) void haar3d_kernel(const float* __restrict__ x,
                                                     float* __restrict__ y) {
    const size_t tid = (size_t)blockIdx.x * 256 + threadIdx.x;
    // wq innermost: 16 w-quads (each quad = 4 output w positions = 8 input floats)
    const int wq = (int)(tid & 15);
    const int h  = (int)((tid >> 4) & 63);
    const int d  = (int)((tid >> 10) & 63);
    const int nc = (int)(tid >> 16);                   // [0,32)

    const size_t row0 = (((size_t)nc * Din + 2 * d) * Hin + 2 * h) * Win + 8 * (size_t)wq;
    const vf4* p00 = (const vf4*)(x + row0);               // i=0, j=0
    const vf4* p01 = (const vf4*)(x + row0 + Win);         // i=0, j=1
    const vf4* p10 = (const vf4*)(x + row0 + HW_IN);       // i=1, j=0
    const vf4* p11 = (const vf4*)(x + row0 + HW_IN + Win); // i=1, j=1

    float A[8], B[8], C[8], D[8];
    {
        vf4 t;
        t = __builtin_nontemporal_load(p00);     A[0]=t.x; A[1]=t.y; A[2]=t.z; A[3]=t.w;
        t = __builtin_nontemporal_load(p00 + 1); A[4]=t.x; A[5]=t.y; A[6]=t.z; A[7]=t.w;
        t = __builtin_nontemporal_load(p01);     B[0]=t.x; B[1]=t.y; B[2]=t.z; B[3]=t.w;
        t = __builtin_nontemporal_load(p01 + 1); B[4]=t.x; B[5]=t.y; B[6]=t.z; B[7]=t.w;
        t = __builtin_nontemporal_load(p10);     C[0]=t.x; C[1]=t.y; C[2]=t.z; C[3]=t.w;
        t = __builtin_nontemporal_load(p10 + 1); C[4]=t.x; C[5]=t.y; C[6]=t.z; C[7]=t.w;
        t = __builtin_nontemporal_load(p11);     D[0]=t.x; D[1]=t.y; D[2]=t.z; D[3]=t.w;
        t = __builtin_nontemporal_load(p11 + 1); D[4]=t.x; D[5]=t.y; D[6]=t.z; D[7]=t.w;
    }

    // Butterfly per w-pair. o bits: bit2 = i(d) hi, bit1 = j(h) hi, bit0 = k(w) hi.
    float out[8][4];
#pragma unroll
    for (int p = 0; p < 4; ++p) {
        const int e0 = 2 * p, e1 = 2 * p + 1;
        float klA = A[e0] + A[e1], khA = A[e0] - A[e1];
        float klB = B[e0] + B[e1], khB = B[e0] - B[e1];
        float klC = C[e0] + C[e1], khC = C[e0] - C[e1];
        float klD = D[e0] + D[e1], khD = D[e0] - D[e1];
        float jlkl0 = klA + klB, jhkl0 = klA - klB;
        float jlkh0 = khA + khB, jhkh0 = khA - khB;
        float jlkl1 = klC + klD, jhkl1 = klC - klD;
        float jlkh1 = khC + khD, jhkh1 = khC - khD;
        out[0][p] = (jlkl0 + jlkl1) * 0.125f;
        out[1][p] = (jlkh0 + jlkh1) * 0.125f;
        out[2][p] = (jhkl0 + jhkl1) * 0.125f;
        out[3][p] = (jhkh0 + jhkh1) * 0.125f;
        out[4][p] = (jlkl0 - jlkl1) * 0.125f;
        out[5][p] = (jlkh0 - jlkh1) * 0.125f;
        out[6][p] = (jhkl0 - jhkl1) * 0.125f;
        out[7][p] = (jhkh0 - jhkh1) * 0.125f;
    }

    // y[((nc*8 + o)*64 + d)*4096 + h*64 + 4*wq], one vf4 per o-plane
    const size_t obase = (size_t)nc * 8 * PLANE_OUT + (size_t)d * (H2 * W2)
                       + (size_t)h * W2 + 4 * (size_t)wq;
#pragma unroll
    for (int o = 0; o < 8; ++o) {
        vf4 r;
        r.x = out[o][0]; r.y = out[o][1]; r.z = out[o][2]; r.w = out[o][3];
        __builtin_nontemporal_store(r, (vf4*)(y + obase + (size_t)o * PLANE_OUT));
    }
}

extern "C" void kernel_launch(void* const* d_in, const int* in_sizes, int n_in,
                              void* d_out, int out_size, void* d_ws, size_t ws_size,
                              hipStream_t stream) {
    const float* x = (const float*)d_in[0];
    float* y = (float*)d_out;
    // total threads: 32 * 64 * 64 * 16 = 2,097,152 -> 8192 blocks of 256
    const int total = NC * D2 * H2 * (W2 / 4);
    haar3d_kernel<<<total / 256, 256, 0, stream>>>(x, y);
}